// Round 9
// baseline (255.850 us; speedup 1.0000x reference)
//
#include <hip/hip_runtime.h>
#include <math.h>

#define DIMM 256
#define HEADS 8
#define NB 2048
#define BB 2
#define ROWS (BB*NB)   // 4096

typedef __attribute__((ext_vector_type(8))) short bf16x8;
typedef __attribute__((ext_vector_type(4))) short bf16x4;
typedef __attribute__((ext_vector_type(4))) float f32x4;

__device__ inline unsigned short f2bf(float f) {
    unsigned int u = __float_as_uint(f);
    u += 0x7FFFu + ((u >> 16) & 1u);           // RNE
    return (unsigned short)(u >> 16);
}
__device__ inline float bf2f(unsigned short u) {
    return __uint_as_float(((unsigned int)u) << 16);
}

__device__ inline int get_mask(const void* nm, int fmt, int idx) {
    if (fmt) return ((const unsigned char*)nm)[idx] != 0;
    return ((const int*)nm)[idx] != 0;
}

// ---------------- LayerNorm body, bf16 out ----------------
__device__ inline void ln8_body(const float* __restrict__ x, const float* __restrict__ g,
                                const float* __restrict__ bb, unsigned short* __restrict__ o,
                                int row, int lane32) {
    int c0 = lane32 * 8;
    float4 v0 = *(const float4*)&x[(size_t)row * DIMM + c0];
    float4 v1 = *(const float4*)&x[(size_t)row * DIMM + c0 + 4];
    float s  = v0.x + v0.y + v0.z + v0.w + v1.x + v1.y + v1.z + v1.w;
    float s2 = v0.x*v0.x + v0.y*v0.y + v0.z*v0.z + v0.w*v0.w
             + v1.x*v1.x + v1.y*v1.y + v1.z*v1.z + v1.w*v1.w;
#pragma unroll
    for (int off = 16; off >= 1; off >>= 1) {
        s  += __shfl_xor(s,  off);
        s2 += __shfl_xor(s2, off);
    }
    float mean = s * (1.0f / DIMM);
    float var  = s2 * (1.0f / DIMM) - mean * mean;
    float rstd = rsqrtf(var + 1e-5f);
    float4 g0 = *(const float4*)&g[c0],  g1 = *(const float4*)&g[c0 + 4];
    float4 b0 = *(const float4*)&bb[c0], b1 = *(const float4*)&bb[c0 + 4];
    ushort4 u0, u1;
    u0.x = f2bf((v0.x - mean) * rstd * g0.x + b0.x);
    u0.y = f2bf((v0.y - mean) * rstd * g0.y + b0.y);
    u0.z = f2bf((v0.z - mean) * rstd * g0.z + b0.z);
    u0.w = f2bf((v0.w - mean) * rstd * g0.w + b0.w);
    u1.x = f2bf((v1.x - mean) * rstd * g1.x + b1.x);
    u1.y = f2bf((v1.y - mean) * rstd * g1.y + b1.y);
    u1.z = f2bf((v1.z - mean) * rstd * g1.z + b1.z);
    u1.w = f2bf((v1.w - mean) * rstd * g1.w + b1.w);
    *(ushort4*)&o[(size_t)row * DIMM + c0]     = u0;
    *(ushort4*)&o[(size_t)row * DIMM + c0 + 4] = u1;
}

// ---------------- prep: w2bfT (0..191) + LN1 (192..703) + emaskP (704..2751) ----------
// emaskP: per (b, qt16, kt) unit of 1024B. Lane L holds int4 at L*16:
// dword t16, byte r = code for [q = qt16*16 + (L&15)][key = kt*64 + t16*16 + (L>>4)*4 + r]
__global__ __launch_bounds__(256) void prep_kernel(
    const float* __restrict__ w0, const float* __restrict__ w1,
    const float* __restrict__ w2, const float* __restrict__ w3,
    unsigned short* __restrict__ o0, unsigned short* __restrict__ o1,
    unsigned short* __restrict__ o2, unsigned short* __restrict__ o3,
    const float* __restrict__ x, const float* __restrict__ ln1_g,
    const float* __restrict__ ln1_b, unsigned short* __restrict__ h_ln,
    const int* __restrict__ etypes, const void* __restrict__ nmask,
    unsigned char* __restrict__ emaskP)
{
    __shared__ float tile[64][65];
    __shared__ int fsh;
    int bid = blockIdx.x, t = threadIdx.x;
    if (bid < 192) {
        const float* src; unsigned short* dst; int K, N, idx;
        if (bid < 48)       { src = w0; dst = o0; K = 256;  N = 768;  idx = bid; }
        else if (bid < 64)  { src = w1; dst = o1; K = 256;  N = 256;  idx = bid - 48; }
        else if (bid < 128) { src = w2; dst = o2; K = 256;  N = 1024; idx = bid - 64; }
        else                { src = w3; dst = o3; K = 1024; N = 256;  idx = bid - 128; }
        int ntiles = N >> 6;
        int k0 = (idx / ntiles) * 64, n0 = (idx % ntiles) * 64;
        int r = t >> 4, c4 = (t & 15) * 4;
#pragma unroll
        for (int i = 0; i < 4; ++i) {
            float4 v = *(const float4*)&src[(size_t)(k0 + r + i * 16) * N + n0 + c4];
            tile[r + i * 16][c4 + 0] = v.x;
            tile[r + i * 16][c4 + 1] = v.y;
            tile[r + i * 16][c4 + 2] = v.z;
            tile[r + i * 16][c4 + 3] = v.w;
        }
        __syncthreads();
#pragma unroll
        for (int i = 0; i < 4; ++i) {
            int n = n0 + r + i * 16;
            ushort4 u;
            u.x = f2bf(tile[c4 + 0][r + i * 16]);
            u.y = f2bf(tile[c4 + 1][r + i * 16]);
            u.z = f2bf(tile[c4 + 2][r + i * 16]);
            u.w = f2bf(tile[c4 + 3][r + i * 16]);
            *(ushort4*)&dst[(size_t)n * K + k0 + c4] = u;
        }
    } else if (bid < 704) {
        int row = (bid - 192) * 8 + (t >> 5);
        ln8_body(x, ln1_g, ln1_b, h_ln, row, t & 31);
    } else {
        if (t == 0) fsh = 0;
        __syncthreads();
        if (((const unsigned char*)nmask)[4 * t + 1] != 0) fsh = 1;
        __syncthreads();
        int fm = fsh;
        int unit = (bid - 704) * 4 + (t >> 6);
        int lane = t & 63, quad = lane >> 4, l15 = lane & 15;
        int b = unit >> 12;                 // 4096 units per batch
        int qt16 = (unit >> 5) & 127;
        int kt = unit & 31;
        int qr = qt16 * 16 + l15;
        int rowv = get_mask(nmask, fm, b * NB + qr);
        const int* erow = etypes + (size_t)(b * NB + qr) * NB;
        int dw[4];
#pragma unroll
        for (int t16 = 0; t16 < 4; ++t16) {
            int col0 = kt * 64 + t16 * 16 + quad * 4;
            int4 e4 = *(const int4*)(erow + col0);
            int ee[4] = {e4.x, e4.y, e4.z, e4.w};
            int cv[4];
            if (fm) {
                unsigned int m4 = *(const unsigned int*)((const unsigned char*)nmask + b * NB + col0);
                cv[0] = (m4 & 0xffu) != 0;     cv[1] = (m4 & 0xff00u) != 0;
                cv[2] = (m4 & 0xff0000u) != 0; cv[3] = (m4 >> 24) != 0;
            } else {
                int4 m4 = *(const int4*)((const int*)nmask + b * NB + col0);
                cv[0] = m4.x != 0; cv[1] = m4.y != 0; cv[2] = m4.z != 0; cv[3] = m4.w != 0;
            }
            unsigned int pk = 0u;
#pragma unroll
            for (int r = 0; r < 4; ++r) {
                int col = col0 + r;
                int valid = rowv && cv[r] && ((ee[r] != 0) || (col == qr));
                pk |= (valid ? (unsigned int)(ee[r] + 1) : 0u) << (r * 8);
            }
            dw[t16] = (int)pk;
        }
        int4 o = {dw[0], dw[1], dw[2], dw[3]};
        *(int4*)(emaskP + (size_t)unit * 1024 + lane * 16) = o;
    }
}

// ---------------- MFMA qkv GEMM (64x64); q columns pre-scaled by 1/sqrt(d) ----------
__global__ __launch_bounds__(256) void gemm_qkv_mfma(
    const unsigned short* __restrict__ A, const unsigned short* __restrict__ Bt,
    const float* __restrict__ bias,
    unsigned short* __restrict__ qkvh, unsigned short* __restrict__ vT)
{
    const int K = 256;
    int t = threadIdx.x, w = t >> 6, l = t & 63;
    int l15 = l & 15, quad = l >> 4;
    int n0 = blockIdx.x * 64;
    int m0 = blockIdx.y * 64;
    const unsigned short* ap = A + (size_t)(m0 + w * 16 + l15) * K + quad * 8;
    const unsigned short* bp = Bt + (size_t)(n0 + l15) * K + quad * 8;

    f32x4 acc[4];
#pragma unroll
    for (int c = 0; c < 4; ++c) acc[c] = (f32x4){0.f, 0.f, 0.f, 0.f};

    bf16x8 aA, bA[4], aB, bB[4];
    auto ld = [&](bf16x8& af, bf16x8 (&bf)[4], int k0) {
        af = *(const bf16x8*)(ap + k0);
#pragma unroll
        for (int c = 0; c < 4; ++c)
            bf[c] = *(const bf16x8*)(bp + (size_t)(c * 16) * K + k0);
    };
    auto pr = [&](const bf16x8& af, const bf16x8 (&bf)[4]) {
#pragma unroll
        for (int c = 0; c < 4; ++c)
            acc[c] = __builtin_amdgcn_mfma_f32_16x16x32_bf16(af, bf[c], acc[c], 0, 0, 0);
    };
    ld(aA, bA, 0);
    for (int k0 = 0; k0 < K; k0 += 64) {
        ld(aB, bB, k0 + 32);
        pr(aA, bA);
        if (k0 + 64 < K) ld(aA, bA, k0 + 64);
        pr(aB, bB);
    }

    if (n0 < 512) {
        float sc = (n0 < 256) ? 0.17677669529663689f : 1.0f;   // fold 1/sqrt(32) into q
#pragma unroll
        for (int r = 0; r < 4; ++r) {
            int row = m0 + w * 16 + quad * 4 + r;
#pragma unroll
            for (int c = 0; c < 4; ++c) {
                int col = n0 + c * 16 + l15;
                qkvh[(size_t)row * 512 + col] = f2bf((acc[c][r] + bias[col]) * sc);
            }
        }
    } else {
        int bb_ = m0 >> 11;
        int n = (m0 + w * 16 + quad * 4) & 2047;
#pragma unroll
        for (int c = 0; c < 4; ++c) {
            int col = n0 + c * 16 + l15 - 512;
            int hidx = col >> 5, d = col & 31;
            float bs = bias[n0 + c * 16 + l15];
            ushort4 u;
            u.x = f2bf(acc[c][0] + bs);
            u.y = f2bf(acc[c][1] + bs);
            u.z = f2bf(acc[c][2] + bs);
            u.w = f2bf(acc[c][3] + bs);
            *(ushort4*)&vT[(size_t)((bb_ * HEADS + hidx) * 32 + d) * NB + n] = u;
        }
    }
}

// ---------------- MFMA attention: S^T form, zero-LDS k-loop, split-K=4 ----------------
// S^T = mfma16x16x32(A=K, B=Q) -> C row=key(quad*4+r), col=q(l15).
// P^T regs are exactly the B-frag of mfma_16x16x16_bf16 (k=quad*4+j).
// O^T = mfma16x16x16(A=V^T half, B=P^T): D row=d_local, col=q.
__global__ __launch_bounds__(256) void attn_mfma(
    const unsigned short* __restrict__ qkvh,  // [4096][512] bf16: q(scaled)|k
    const unsigned short* __restrict__ vT,    // [512][2048] bf16
    const unsigned char* __restrict__ emaskP, // permuted codes (see prep)
    const float* __restrict__ table,
    unsigned short* __restrict__ OpH, float* __restrict__ lpart)
{
    __shared__ float tab2m[16];               // exp(table) multipliers; [0]=0

    int t = threadIdx.x;
    int w = t >> 6, l = t & 63;
    int l15 = l & 15, quad = l >> 4;
    int h = blockIdx.y;
    int z = blockIdx.z, b = z >> 2, sp = z & 3;
    int q0 = blockIdx.x * 64 + w * 16;
    int kbase = sp * (NB / 4), kend = kbase + NB / 4;

    if (t < 16) tab2m[t] = (t >= 1 && t < 10) ? __expf(table[(t - 1) * 8 + h]) : 0.f;
    __syncthreads();

    // Q B-frag (pre-scaled)
    bf16x8 bq = *(const bf16x8*)(qkvh + (size_t)(b * NB + q0 + l15) * 512 + h * 32 + quad * 8);

    const unsigned short* kp  = qkvh + (size_t)(b * NB + l15) * 512 + 256 + h * 32 + quad * 8;
    const unsigned short* vp0 = vT + (size_t)((b * HEADS + h) * 32 + l15) * NB + quad * 4;
    const unsigned short* vp1 = vp0 + (size_t)16 * NB;
    int qt16 = blockIdx.x * 4 + w;
    const unsigned char* ep = emaskP + (size_t)((b * 128 + qt16) * 32) * 1024 + l * 16;

    float lacc = 0.f;
    f32x4 O0 = {0.f, 0.f, 0.f, 0.f}, O1 = {0.f, 0.f, 0.f, 0.f};

    bf16x8 kA[4], kB[4];
    bf16x4 vA[4][2], vB[4][2];
    int4 eA, eB;

    auto loadtile = [&](bf16x8 (&kf)[4], bf16x4 (&vf)[4][2], int4& ef, int m0) {
#pragma unroll
        for (int t16 = 0; t16 < 4; ++t16) {
            kf[t16]    = *(const bf16x8*)(kp + (size_t)(m0 + t16 * 16) * 512);
            vf[t16][0] = *(const bf16x4*)(vp0 + m0 + t16 * 16);
            vf[t16][1] = *(const bf16x4*)(vp1 + m0 + t16 * 16);
        }
        ef = *(const int4*)(ep + (size_t)(m0 >> 6) * 1024);
    };

    auto process = [&](const bf16x8 (&kf)[4], const bf16x4 (&vf)[4][2], const int4& ef) {
        int ew[4] = {ef.x, ef.y, ef.z, ef.w};
#pragma unroll
        for (int t16 = 0; t16 < 4; ++t16) {
            f32x4 zero = {0.f, 0.f, 0.f, 0.f};
            f32x4 sT = __builtin_amdgcn_mfma_f32_16x16x32_bf16(kf[t16], bq, zero, 0, 0, 0);
            unsigned int e = (unsigned int)ew[t16];
            float p0 = __expf(sT[0]) * tab2m[e & 0xffu];
            float p1 = __expf(sT[1]) * tab2m[(e >> 8) & 0xffu];
            float p2 = __expf(sT[2]) * tab2m[(e >> 16) & 0xffu];
            float p3 = __expf(sT[3]) * tab2m[e >> 24];
            lacc += (p0 + p1) + (p2 + p3);
            bf16x4 pb;
            pb[0] = (short)f2bf(p0); pb[1] = (short)f2bf(p1);
            pb[2] = (short)f2bf(p2); pb[3] = (short)f2bf(p3);
            O0 = __builtin_amdgcn_mfma_f32_16x16x16bf16_1k(vf[t16][0], pb, O0, 0, 0, 0);
            O1 = __builtin_amdgcn_mfma_f32_16x16x16bf16_1k(vf[t16][1], pb, O1, 0, 0, 0);
        }
    };

    loadtile(kA, vA, eA, kbase);
    for (int m0 = kbase; m0 < kend; m0 += 128) {
        loadtile(kB, vB, eB, m0 + 64);
        process(kA, vA, eA);
        if (m0 + 128 < kend) loadtile(kA, vA, eA, m0 + 128);
        process(kB, vB, eB);
    }

    lacc += __shfl_xor(lacc, 16);
    lacc += __shfl_xor(lacc, 32);

    unsigned short* Ob = OpH + (size_t)sp * ROWS * DIMM;
    int row = b * NB + q0 + l15;
    ushort4 u0, u1;
    u0.x = f2bf(O0[0]); u0.y = f2bf(O0[1]); u0.z = f2bf(O0[2]); u0.w = f2bf(O0[3]);
    u1.x = f2bf(O1[0]); u1.y = f2bf(O1[1]); u1.z = f2bf(O1[2]); u1.w = f2bf(O1[3]);
    *(ushort4*)&Ob[(size_t)row * DIMM + h * 32 + quad * 4]      = u0;
    *(ushort4*)&Ob[(size_t)row * DIMM + h * 32 + 16 + quad * 4] = u1;
    if (quad == 0) lpart[(size_t)sp * ROWS * 8 + (size_t)row * 8 + h] = lacc;
}

// ---------------- megaback: combine+proj+resid+mask+LN2+ffn1+gelu+ffn2+resid --------
__global__ __launch_bounds__(1024) void megaback(
    const unsigned short* __restrict__ OpH, const float* __restrict__ lpart,
    const unsigned short* __restrict__ projT, const float* __restrict__ proj_b,
    const float* __restrict__ x, const void* __restrict__ nmask,
    const float* __restrict__ g2, const float* __restrict__ b2,
    const unsigned short* __restrict__ f1T, const float* __restrict__ ffn_b1,
    const unsigned short* __restrict__ f2T, const float* __restrict__ ffn_b2,
    float* __restrict__ out)
{
    __shared__ float rinv_l[16][8];
    __shared__ float stats[16][2];
    __shared__ float redn[16][16][2];
    __shared__ unsigned short Astage[16][264];
    __shared__ float x1s[16][260];
    __shared__ unsigned short hstage[16][264];
    __shared__ unsigned short midstage[16][1032];
    __shared__ int fsh;

    int t = threadIdx.x;
    int w = t >> 6, l = t & 63;
    int l15 = l & 15, quad = l >> 4;
    int grow0 = blockIdx.x * 16;

    if (t == 0) fsh = 0;
    __syncthreads();
    if (((const unsigned char*)nmask)[4 * t + 1] != 0) fsh = 1;

    if (t < 128) {
        int row = t >> 3, h = t & 7;
        float s = 0.f;
#pragma unroll
        for (int sp = 0; sp < 4; ++sp)
            s += lpart[(size_t)sp * ROWS * 8 + (size_t)(grow0 + row) * 8 + h];
        rinv_l[row][h] = (s > 0.f) ? 1.f / s : 0.f;
    }
    __syncthreads();
    int fm = fsh;

    {
        int row = t >> 6, col4 = (t & 63) * 4;
        float rinv = rinv_l[row][col4 >> 5];
        float o0 = 0.f, o1 = 0.f, o2 = 0.f, o3 = 0.f;
#pragma unroll
        for (int sp = 0; sp < 4; ++sp) {
            ushort4 u = *(const ushort4*)&OpH[(size_t)sp * ROWS * DIMM +
                                             (size_t)(grow0 + row) * DIMM + col4];
            o0 += bf2f(u.x); o1 += bf2f(u.y); o2 += bf2f(u.z); o3 += bf2f(u.w);
        }
        ushort4 u;
        u.x = f2bf(o0 * rinv); u.y = f2bf(o1 * rinv);
        u.z = f2bf(o2 * rinv); u.w = f2bf(o3 * rinv);
        *(ushort4*)&Astage[row][col4] = u;
    }
    __syncthreads();

    {
        int col = w * 16 + l15;
        f32x4 acc = (f32x4){0.f, 0.f, 0.f, 0.f};
        const unsigned short* bp = projT + (size_t)col * 256 + quad * 8;
        bf16x8 sb[4];
#pragma unroll
        for (int i = 0; i < 4; ++i) sb[i] = *(const bf16x8*)(bp + i * 32);
#pragma unroll
        for (int ch = 0; ch < 8; ++ch) {
            bf16x8 a = *(const bf16x8*)&Astage[l15][ch * 32 + quad * 8];
            acc = __builtin_amdgcn_mfma_f32_16x16x32_bf16(a, sb[ch & 3], acc, 0, 0, 0);
            if (ch + 4 < 8) sb[ch & 3] = *(const bf16x8*)(bp + (ch + 4) * 32);
        }
        float bs = proj_b[col];
#pragma unroll
        for (int r = 0; r < 4; ++r) {
            int row = quad * 4 + r, grow = grow0 + row;
            float mk = (float)get_mask(nmask, fm, grow);
            float v = (acc[r] + bs) * mk + x[(size_t)grow * DIMM + col];
            x1s[row][col] = v;
            float s = v, s2 = v * v;
#pragma unroll
            for (int off = 1; off < 16; off <<= 1) {
                s += __shfl_xor(s, off); s2 += __shfl_xor(s2, off);
            }
            if (l15 == 0) { redn[row][w][0] = s; redn[row][w][1] = s2; }
        }
    }
    __syncthreads();
    if (t < 16) {
        float s = 0.f, s2 = 0.f;
#pragma unroll
        for (int ww = 0; ww < 16; ++ww) { s += redn[t][ww][0]; s2 += redn[t][ww][1]; }
        float mean = s * (1.f / DIMM);
        float var  = s2 * (1.f / DIMM) - mean * mean;
        stats[t][0] = mean; stats[t][1] = rsqrtf(var + 1e-5f);
    }
    __syncthreads();

    {
        int col = w * 16 + l15;
        float gv = g2[col], bv = b2[col];
#pragma unroll
        for (int r = 0; r < 4; ++r) {
            int row = quad * 4 + r;
            float hv = (x1s[row][col] - stats[row][0]) * stats[row][1] * gv + bv;
            hstage[row][col] = f2bf(hv);
        }
    }
    __syncthreads();

    {
        f32x4 acc[4];
#pragma unroll
        for (int c = 0; c < 4; ++c) acc[c] = (f32x4){0.f, 0.f, 0.f, 0.f};
        const unsigned short* bp = f1T + (size_t)(w * 64 + l15) * 256 + quad * 8;
        bf16x8 bA[4], bB[4];
#pragma unroll
        for (int c = 0; c < 4; ++c) bA[c] = *(const bf16x8*)(bp + (size_t)(c * 16) * 256);
#pragma unroll
        for (int ch = 0; ch < 8; ++ch) {
            bf16x8 a = *(const bf16x8*)&hstage[l15][ch * 32 + quad * 8];
            if (ch + 1 < 8) {
#pragma unroll
                for (int c = 0; c < 4; ++c)
                    bB[c] = *(const bf16x8*)(bp + (size_t)(c * 16) * 256 + (ch + 1) * 32);
            }
#pragma unroll
            for (int c = 0; c < 4; ++c)
                acc[c] = __builtin_amdgcn_mfma_f32_16x16x32_bf16(a, bA[c], acc[c], 0, 0, 0);
#pragma unroll
            for (int c = 0; c < 4; ++c) bA[c] = bB[c];
        }
#pragma unroll
        for (int c = 0; c < 4; ++c) {
            int col = w * 64 + c * 16 + l15;
            float bs = ffn_b1[col];
#pragma unroll
            for (int r = 0; r < 4; ++r) {
                float v = acc[c][r] + bs;
                float x2 = v * v;
                float p = v * fmaf(0.07135481f, x2, 1.5957691f);
                float e = __expf(p);
                float gl = v * (e / (e + 1.f));
                midstage[quad * 4 + r][col] = f2bf(gl);
            }
        }
    }
    __syncthreads();

    {
        int col = w * 16 + l15;
        f32x4 acc = (f32x4){0.f, 0.f, 0.f, 0.f};
        const unsigned short* bp = f2T + (size_t)col * 1024 + quad * 8;
        bf16x8 sb[4];
#pragma unroll
        for (int i = 0; i < 4; ++i) sb[i] = *(const bf16x8*)(bp + i * 32);
#pragma unroll
        for (int ch = 0; ch < 32; ++ch) {
            bf16x8 a = *(const bf16x8*)&midstage[l15][ch * 32 + quad * 8];
            acc = __builtin_amdgcn_mfma_f32_16x16x32_bf16(a, sb[ch & 3], acc, 0, 0, 0);
            if (ch + 4 < 32) sb[ch & 3] = *(const bf16x8*)(bp + (ch + 4) * 32);
        }
        float bs = ffn_b2[col];
#pragma unroll
        for (int r = 0; r < 4; ++r) {
            int row = quad * 4 + r, grow = grow0 + row;
            float mk = (float)get_mask(nmask, fm, grow);
            out[(size_t)grow * DIMM + col] = x1s[row][col] + (acc[r] + bs) * mk;
        }
    }
}

// ---------------- launch ----------------
extern "C" void kernel_launch(void* const* d_in, const int* in_sizes, int n_in,
                              void* d_out, int out_size, void* d_ws, size_t ws_size,
                              hipStream_t stream) {
    const float* x       = (const float*)d_in[0];
    const int*   etypes  = (const int*)d_in[1];
    const void*  nmask   = d_in[2];
    const float* qkv_w   = (const float*)d_in[3];
    const float* qkv_b   = (const float*)d_in[4];
    const float* proj_w  = (const float*)d_in[5];
    const float* proj_b  = (const float*)d_in[6];
    const float* table   = (const float*)d_in[7];
    const float* ln1_g   = (const float*)d_in[8];
    const float* ln1_b   = (const float*)d_in[9];
    const float* ln2_g   = (const float*)d_in[10];
    const float* ln2_b   = (const float*)d_in[11];
    const float* ffn_w1  = (const float*)d_in[12];
    const float* ffn_b1  = (const float*)d_in[13];
    const float* ffn_w2  = (const float*)d_in[14];
    const float* ffn_b2  = (const float*)d_in[15];
    float* out = (float*)d_out;
    float* ws  = (float*)d_ws;

    float* lpart = ws;                               // 131,072 f (512 KB)
    unsigned short* ub = (unsigned short*)(ws + 131072);
    unsigned short* h_ln   = ub;                     // 1,048,576 us
    unsigned short* qkvh   = ub + 1048576;           // 2,097,152
    unsigned short* vT     = ub + 3145728;           // 1,048,576
    unsigned short* OpH    = ub + 4194304;           // 4,194,304 (4 splits)
    unsigned short* qkvT   = ub + 8388608;           // 196,608
    unsigned short* projT  = ub + 8585216;           // 65,536
    unsigned short* f1T    = ub + 8650752;           // 262,144
    unsigned short* f2T    = ub + 8912896;           // 262,144
    unsigned char* emaskP  = (unsigned char*)(ub + 9175040);  // 8,388,608 B

    prep_kernel<<<dim3(2752), dim3(256), 0, stream>>>(
        qkv_w, proj_w, ffn_w1, ffn_w2, qkvT, projT, f1T, f2T,
        x, ln1_g, ln1_b, h_ln, etypes, nmask, emaskP);
    gemm_qkv_mfma<<<dim3(12, 64), dim3(256), 0, stream>>>(h_ln, qkvT, qkv_b, qkvh, vT);
    attn_mfma<<<dim3(NB/64, HEADS, BB*4), dim3(256), 0, stream>>>(
        qkvh, vT, emaskP, table, OpH, lpart);
    megaback<<<dim3(ROWS/16), dim3(1024), 0, stream>>>(
        OpH, lpart, projT, proj_b, x, nmask, ln2_g, ln2_b,
        f1T, ffn_b1, f2T, ffn_b2, out);
}

// Round 10
// 230.062 us; speedup vs baseline: 1.1121x; 1.1121x over previous
//
#include <hip/hip_runtime.h>
#include <math.h>

#define DIMM 256
#define HEADS 8
#define NB 2048
#define BB 2
#define ROWS (BB*NB)   // 4096

typedef __attribute__((ext_vector_type(8))) short bf16x8;
typedef __attribute__((ext_vector_type(4))) short bf16x4;
typedef __attribute__((ext_vector_type(4))) float f32x4;

__device__ inline unsigned short f2bf(float f) {
    unsigned int u = __float_as_uint(f);
    u += 0x7FFFu + ((u >> 16) & 1u);           // RNE
    return (unsigned short)(u >> 16);
}
__device__ inline float bf2f(unsigned short u) {
    return __uint_as_float(((unsigned int)u) << 16);
}

__device__ inline int get_mask(const void* nm, int fmt, int idx) {
    if (fmt) return ((const unsigned char*)nm)[idx] != 0;
    return ((const int*)nm)[idx] != 0;
}

// ---------------- LayerNorm body, bf16 out ----------------
__device__ inline void ln8_body(const float* __restrict__ x, const float* __restrict__ g,
                                const float* __restrict__ bb, unsigned short* __restrict__ o,
                                int row, int lane32) {
    int c0 = lane32 * 8;
    float4 v0 = *(const float4*)&x[(size_t)row * DIMM + c0];
    float4 v1 = *(const float4*)&x[(size_t)row * DIMM + c0 + 4];
    float s  = v0.x + v0.y + v0.z + v0.w + v1.x + v1.y + v1.z + v1.w;
    float s2 = v0.x*v0.x + v0.y*v0.y + v0.z*v0.z + v0.w*v0.w
             + v1.x*v1.x + v1.y*v1.y + v1.z*v1.z + v1.w*v1.w;
#pragma unroll
    for (int off = 16; off >= 1; off >>= 1) {
        s  += __shfl_xor(s,  off);
        s2 += __shfl_xor(s2, off);
    }
    float mean = s * (1.0f / DIMM);
    float var  = s2 * (1.0f / DIMM) - mean * mean;
    float rstd = rsqrtf(var + 1e-5f);
    float4 g0 = *(const float4*)&g[c0],  g1 = *(const float4*)&g[c0 + 4];
    float4 b0 = *(const float4*)&bb[c0], b1 = *(const float4*)&bb[c0 + 4];
    ushort4 u0, u1;
    u0.x = f2bf((v0.x - mean) * rstd * g0.x + b0.x);
    u0.y = f2bf((v0.y - mean) * rstd * g0.y + b0.y);
    u0.z = f2bf((v0.z - mean) * rstd * g0.z + b0.z);
    u0.w = f2bf((v0.w - mean) * rstd * g0.w + b0.w);
    u1.x = f2bf((v1.x - mean) * rstd * g1.x + b1.x);
    u1.y = f2bf((v1.y - mean) * rstd * g1.y + b1.y);
    u1.z = f2bf((v1.z - mean) * rstd * g1.z + b1.z);
    u1.w = f2bf((v1.w - mean) * rstd * g1.w + b1.w);
    *(ushort4*)&o[(size_t)row * DIMM + c0]     = u0;
    *(ushort4*)&o[(size_t)row * DIMM + c0 + 4] = u1;
}

// ---------------- prep: w2bfT (0..191) + LN1 (192..703) + emaskP (704..2751) ----------
// emaskP: per (b, qt16, kt) unit of 1024B. Lane L holds int4 at L*16:
// dword t16, byte r = code for [q = qt16*16 + (L&15)][key = kt*64 + t16*16 + (L>>4)*4 + r]
__global__ __launch_bounds__(256) void prep_kernel(
    const float* __restrict__ w0, const float* __restrict__ w1,
    const float* __restrict__ w2, const float* __restrict__ w3,
    unsigned short* __restrict__ o0, unsigned short* __restrict__ o1,
    unsigned short* __restrict__ o2, unsigned short* __restrict__ o3,
    const float* __restrict__ x, const float* __restrict__ ln1_g,
    const float* __restrict__ ln1_b, unsigned short* __restrict__ h_ln,
    const int* __restrict__ etypes, const void* __restrict__ nmask,
    unsigned char* __restrict__ emaskP)
{
    __shared__ float tile[64][65];
    __shared__ int fsh;
    int bid = blockIdx.x, t = threadIdx.x;
    if (bid < 192) {
        const float* src; unsigned short* dst; int K, N, idx;
        if (bid < 48)       { src = w0; dst = o0; K = 256;  N = 768;  idx = bid; }
        else if (bid < 64)  { src = w1; dst = o1; K = 256;  N = 256;  idx = bid - 48; }
        else if (bid < 128) { src = w2; dst = o2; K = 256;  N = 1024; idx = bid - 64; }
        else                { src = w3; dst = o3; K = 1024; N = 256;  idx = bid - 128; }
        int ntiles = N >> 6;
        int k0 = (idx / ntiles) * 64, n0 = (idx % ntiles) * 64;
        int r = t >> 4, c4 = (t & 15) * 4;
#pragma unroll
        for (int i = 0; i < 4; ++i) {
            float4 v = *(const float4*)&src[(size_t)(k0 + r + i * 16) * N + n0 + c4];
            tile[r + i * 16][c4 + 0] = v.x;
            tile[r + i * 16][c4 + 1] = v.y;
            tile[r + i * 16][c4 + 2] = v.z;
            tile[r + i * 16][c4 + 3] = v.w;
        }
        __syncthreads();
#pragma unroll
        for (int i = 0; i < 4; ++i) {
            int n = n0 + r + i * 16;
            ushort4 u;
            u.x = f2bf(tile[c4 + 0][r + i * 16]);
            u.y = f2bf(tile[c4 + 1][r + i * 16]);
            u.z = f2bf(tile[c4 + 2][r + i * 16]);
            u.w = f2bf(tile[c4 + 3][r + i * 16]);
            *(ushort4*)&dst[(size_t)n * K + k0 + c4] = u;
        }
    } else if (bid < 704) {
        int row = (bid - 192) * 8 + (t >> 5);
        ln8_body(x, ln1_g, ln1_b, h_ln, row, t & 31);
    } else {
        if (t == 0) fsh = 0;
        __syncthreads();
        if (((const unsigned char*)nmask)[4 * t + 1] != 0) fsh = 1;
        __syncthreads();
        int fm = fsh;
        int unit = (bid - 704) * 4 + (t >> 6);
        int lane = t & 63, quad = lane >> 4, l15 = lane & 15;
        int b = unit >> 12;                 // 4096 units per batch
        int qt16 = (unit >> 5) & 127;
        int kt = unit & 31;
        int qr = qt16 * 16 + l15;
        int rowv = get_mask(nmask, fm, b * NB + qr);
        const int* erow = etypes + (size_t)(b * NB + qr) * NB;
        int dw[4];
#pragma unroll
        for (int t16 = 0; t16 < 4; ++t16) {
            int col0 = kt * 64 + t16 * 16 + quad * 4;
            int4 e4 = *(const int4*)(erow + col0);
            int ee[4] = {e4.x, e4.y, e4.z, e4.w};
            int cv[4];
            if (fm) {
                unsigned int m4 = *(const unsigned int*)((const unsigned char*)nmask + b * NB + col0);
                cv[0] = (m4 & 0xffu) != 0;     cv[1] = (m4 & 0xff00u) != 0;
                cv[2] = (m4 & 0xff0000u) != 0; cv[3] = (m4 >> 24) != 0;
            } else {
                int4 m4 = *(const int4*)((const int*)nmask + b * NB + col0);
                cv[0] = m4.x != 0; cv[1] = m4.y != 0; cv[2] = m4.z != 0; cv[3] = m4.w != 0;
            }
            unsigned int pk = 0u;
#pragma unroll
            for (int r = 0; r < 4; ++r) {
                int col = col0 + r;
                int valid = rowv && cv[r] && ((ee[r] != 0) || (col == qr));
                pk |= (valid ? (unsigned int)(ee[r] + 1) : 0u) << (r * 8);
            }
            dw[t16] = (int)pk;
        }
        int4 o = {dw[0], dw[1], dw[2], dw[3]};
        *(int4*)(emaskP + (size_t)unit * 1024 + lane * 16) = o;
    }
}

// ---------------- MFMA qkv GEMM (64x64); q columns pre-scaled by 1/sqrt(d) ----------
__global__ __launch_bounds__(256) void gemm_qkv_mfma(
    const unsigned short* __restrict__ A, const unsigned short* __restrict__ Bt,
    const float* __restrict__ bias,
    unsigned short* __restrict__ qkvh, unsigned short* __restrict__ vT)
{
    const int K = 256;
    int t = threadIdx.x, w = t >> 6, l = t & 63;
    int l15 = l & 15, quad = l >> 4;
    int n0 = blockIdx.x * 64;
    int m0 = blockIdx.y * 64;
    const unsigned short* ap = A + (size_t)(m0 + w * 16 + l15) * K + quad * 8;
    const unsigned short* bp = Bt + (size_t)(n0 + l15) * K + quad * 8;

    f32x4 acc[4];
#pragma unroll
    for (int c = 0; c < 4; ++c) acc[c] = (f32x4){0.f, 0.f, 0.f, 0.f};

    bf16x8 aA, bA[4], aB, bB[4];
    auto ld = [&](bf16x8& af, bf16x8 (&bf)[4], int k0) {
        af = *(const bf16x8*)(ap + k0);
#pragma unroll
        for (int c = 0; c < 4; ++c)
            bf[c] = *(const bf16x8*)(bp + (size_t)(c * 16) * K + k0);
    };
    auto pr = [&](const bf16x8& af, const bf16x8 (&bf)[4]) {
#pragma unroll
        for (int c = 0; c < 4; ++c)
            acc[c] = __builtin_amdgcn_mfma_f32_16x16x32_bf16(af, bf[c], acc[c], 0, 0, 0);
    };
    ld(aA, bA, 0);
    for (int k0 = 0; k0 < K; k0 += 64) {
        ld(aB, bB, k0 + 32);
        pr(aA, bA);
        if (k0 + 64 < K) ld(aA, bA, k0 + 64);
        pr(aB, bB);
    }

    if (n0 < 512) {
        float sc = (n0 < 256) ? 0.17677669529663689f : 1.0f;   // fold 1/sqrt(32) into q
#pragma unroll
        for (int r = 0; r < 4; ++r) {
            int row = m0 + w * 16 + quad * 4 + r;
#pragma unroll
            for (int c = 0; c < 4; ++c) {
                int col = n0 + c * 16 + l15;
                qkvh[(size_t)row * 512 + col] = f2bf((acc[c][r] + bias[col]) * sc);
            }
        }
    } else {
        int bb_ = m0 >> 11;
        int n = (m0 + w * 16 + quad * 4) & 2047;
#pragma unroll
        for (int c = 0; c < 4; ++c) {
            int col = n0 + c * 16 + l15 - 512;
            int hidx = col >> 5, d = col & 31;
            float bs = bias[n0 + c * 16 + l15];
            ushort4 u;
            u.x = f2bf(acc[c][0] + bs);
            u.y = f2bf(acc[c][1] + bs);
            u.z = f2bf(acc[c][2] + bs);
            u.w = f2bf(acc[c][3] + bs);
            *(ushort4*)&vT[(size_t)((bb_ * HEADS + hidx) * 32 + d) * NB + n] = u;
        }
    }
}

// ---------------- MFMA attention: S^T scores + b64 P stage + R6 PV, split-K=4 -------
// Grid (HEADS, qt, z): block_id % 8 == h -> each XCD L2 serves one head's K/V.
// S^T = mfma(A=K, B=Q): C row=key(quad*4+r), col=q(l15) -> lane's 4 P values are
// key-contiguous -> ONE ds_write_b64 per 16-key tile into row-major P[q][key].
// PV identical to R6: A-frag b128 reads of P, B=V^T 16B frags, 16x16x32 MFMAs.
__global__ __launch_bounds__(256) void attn_mfma(
    const unsigned short* __restrict__ qkvh,  // [4096][512] bf16: q(scaled)|k
    const unsigned short* __restrict__ vT,    // [512][2048] bf16
    const unsigned char* __restrict__ emaskP, // permuted codes (see prep)
    const float* __restrict__ table,
    unsigned short* __restrict__ OpH, float* __restrict__ lpart)
{
    __shared__ unsigned short P[4][16][72];   // per-wave probs, row=q, col=key
    __shared__ float tab2m[16];               // exp(table) multipliers; [0]=0

    int t = threadIdx.x;
    int w = t >> 6, l = t & 63;
    int l15 = l & 15, quad = l >> 4;
    int h = blockIdx.x;                       // fastest -> id%8 == h (XCD pin)
    int qt = blockIdx.y;
    int z = blockIdx.z, b = z >> 2, sp = z & 3;
    int q0 = qt * 64 + w * 16;
    int kbase = sp * (NB / 4);

    if (t < 16) tab2m[t] = (t >= 1 && t < 10) ? __expf(table[(t - 1) * 8 + h]) : 0.f;
    __syncthreads();

    // Q B-frag (pre-scaled by 1/sqrt(d))
    bf16x8 bq = *(const bf16x8*)(qkvh + (size_t)(b * NB + q0 + l15) * 512 + h * 32 + quad * 8);

    const unsigned short* kp = qkvh + (size_t)(b * NB + l15) * 512 + 256 + h * 32 + quad * 8;
    const unsigned short* vp = vT + (size_t)((b * HEADS + h) * 32 + l15) * NB + quad * 8;
    int qt16 = qt * 4 + w;
    const unsigned char* ep = emaskP + (size_t)((b * 128 + qt16) * 32) * 1024 + l * 16;

    float lacc = 0.f;
    f32x4 O0 = {0.f, 0.f, 0.f, 0.f}, O1 = {0.f, 0.f, 0.f, 0.f};

    bf16x8 kA[4], kB[4];
    bf16x8 vA[2][2], vB[2][2];
    int4 eA, eB;

    auto loadtile = [&](bf16x8 (&kf)[4], bf16x8 (&vf)[2][2], int4& ef, int m0) {
#pragma unroll
        for (int t16 = 0; t16 < 4; ++t16)
            kf[t16] = *(const bf16x8*)(kp + (size_t)(m0 + t16 * 16) * 512);
#pragma unroll
        for (int ks = 0; ks < 2; ++ks) {
            vf[ks][0] = *(const bf16x8*)(vp + m0 + ks * 32);
            vf[ks][1] = *(const bf16x8*)(vp + 16 * NB + m0 + ks * 32);
        }
        ef = *(const int4*)(ep + (size_t)(m0 >> 6) * 1024);
    };

    auto process = [&](const bf16x8 (&kf)[4], const bf16x8 (&vf)[2][2], const int4& ef) {
        int ew[4] = {ef.x, ef.y, ef.z, ef.w};
        // scores: S^T per 16-key tile; lane holds keys quad*4+r for query l15
#pragma unroll
        for (int t16 = 0; t16 < 4; ++t16) {
            f32x4 zero = {0.f, 0.f, 0.f, 0.f};
            f32x4 sT = __builtin_amdgcn_mfma_f32_16x16x32_bf16(kf[t16], bq, zero, 0, 0, 0);
            unsigned int e = (unsigned int)ew[t16];
            float p0 = __expf(sT[0]) * tab2m[e & 0xffu];
            float p1 = __expf(sT[1]) * tab2m[(e >> 8) & 0xffu];
            float p2 = __expf(sT[2]) * tab2m[(e >> 16) & 0xffu];
            float p3 = __expf(sT[3]) * tab2m[e >> 24];
            lacc += (p0 + p1) + (p2 + p3);
            bf16x4 pb;
            pb[0] = (short)f2bf(p0); pb[1] = (short)f2bf(p1);
            pb[2] = (short)f2bf(p2); pb[3] = (short)f2bf(p3);
            *(bf16x4*)&P[w][l15][t16 * 16 + quad * 4] = pb;   // one b64 write
        }
        // PV: A-frags b128 from P (same wave, no barrier), B=V^T frags
#pragma unroll
        for (int ks = 0; ks < 2; ++ks) {
            bf16x8 pa = *(const bf16x8*)&P[w][l15][ks * 32 + quad * 8];
            O0 = __builtin_amdgcn_mfma_f32_16x16x32_bf16(pa, vf[ks][0], O0, 0, 0, 0);
            O1 = __builtin_amdgcn_mfma_f32_16x16x32_bf16(pa, vf[ks][1], O1, 0, 0, 0);
        }
    };

    loadtile(kA, vA, eA, kbase);
    for (int m0 = kbase; m0 < kbase + NB / 4; m0 += 128) {
        loadtile(kB, vB, eB, m0 + 64);
        process(kA, vA, eA);
        if (m0 + 128 < kbase + NB / 4) loadtile(kA, vA, eA, m0 + 128);
        process(kB, vB, eB);
    }

    // row-sum for query l15: sum over quads
    lacc += __shfl_xor(lacc, 16);
    lacc += __shfl_xor(lacc, 32);

    unsigned short* Ob = OpH + (size_t)sp * ROWS * DIMM;
#pragma unroll
    for (int r = 0; r < 4; ++r) {
        int row = b * NB + q0 + quad * 4 + r;
        Ob[(size_t)row * DIMM + h * 32 + l15]      = f2bf(O0[r]);
        Ob[(size_t)row * DIMM + h * 32 + 16 + l15] = f2bf(O1[r]);
    }
    if (quad == 0) {
        int row = b * NB + q0 + l15;
        lpart[(size_t)sp * ROWS * 8 + (size_t)row * 8 + h] = lacc;
    }
}

// ---------------- megaback: combine+proj+resid+mask+LN2+ffn1+gelu+ffn2+resid --------
__global__ __launch_bounds__(1024) void megaback(
    const unsigned short* __restrict__ OpH, const float* __restrict__ lpart,
    const unsigned short* __restrict__ projT, const float* __restrict__ proj_b,
    const float* __restrict__ x, const void* __restrict__ nmask,
    const float* __restrict__ g2, const float* __restrict__ b2,
    const unsigned short* __restrict__ f1T, const float* __restrict__ ffn_b1,
    const unsigned short* __restrict__ f2T, const float* __restrict__ ffn_b2,
    float* __restrict__ out)
{
    __shared__ float rinv_l[16][8];
    __shared__ float stats[16][2];
    __shared__ float redn[16][16][2];
    __shared__ unsigned short Astage[16][264];
    __shared__ float x1s[16][260];
    __shared__ unsigned short hstage[16][264];
    __shared__ unsigned short midstage[16][1032];
    __shared__ int fsh;

    int t = threadIdx.x;
    int w = t >> 6, l = t & 63;
    int l15 = l & 15, quad = l >> 4;
    int grow0 = blockIdx.x * 16;

    if (t == 0) fsh = 0;
    __syncthreads();
    if (((const unsigned char*)nmask)[4 * t + 1] != 0) fsh = 1;

    if (t < 128) {
        int row = t >> 3, h = t & 7;
        float s = 0.f;
#pragma unroll
        for (int sp = 0; sp < 4; ++sp)
            s += lpart[(size_t)sp * ROWS * 8 + (size_t)(grow0 + row) * 8 + h];
        rinv_l[row][h] = (s > 0.f) ? 1.f / s : 0.f;
    }
    __syncthreads();
    int fm = fsh;

    {
        int row = t >> 6, col4 = (t & 63) * 4;
        float rinv = rinv_l[row][col4 >> 5];
        float o0 = 0.f, o1 = 0.f, o2 = 0.f, o3 = 0.f;
#pragma unroll
        for (int sp = 0; sp < 4; ++sp) {
            ushort4 u = *(const ushort4*)&OpH[(size_t)sp * ROWS * DIMM +
                                             (size_t)(grow0 + row) * DIMM + col4];
            o0 += bf2f(u.x); o1 += bf2f(u.y); o2 += bf2f(u.z); o3 += bf2f(u.w);
        }
        ushort4 u;
        u.x = f2bf(o0 * rinv); u.y = f2bf(o1 * rinv);
        u.z = f2bf(o2 * rinv); u.w = f2bf(o3 * rinv);
        *(ushort4*)&Astage[row][col4] = u;
    }
    __syncthreads();

    {
        int col = w * 16 + l15;
        f32x4 acc = (f32x4){0.f, 0.f, 0.f, 0.f};
        const unsigned short* bp = projT + (size_t)col * 256 + quad * 8;
        bf16x8 sb[4];
#pragma unroll
        for (int i = 0; i < 4; ++i) sb[i] = *(const bf16x8*)(bp + i * 32);
#pragma unroll
        for (int ch = 0; ch < 8; ++ch) {
            bf16x8 a = *(const bf16x8*)&Astage[l15][ch * 32 + quad * 8];
            acc = __builtin_amdgcn_mfma_f32_16x16x32_bf16(a, sb[ch & 3], acc, 0, 0, 0);
            if (ch + 4 < 8) sb[ch & 3] = *(const bf16x8*)(bp + (ch + 4) * 32);
        }
        float bs = proj_b[col];
#pragma unroll
        for (int r = 0; r < 4; ++r) {
            int row = quad * 4 + r, grow = grow0 + row;
            float mk = (float)get_mask(nmask, fm, grow);
            float v = (acc[r] + bs) * mk + x[(size_t)grow * DIMM + col];
            x1s[row][col] = v;
            float s = v, s2 = v * v;
#pragma unroll
            for (int off = 1; off < 16; off <<= 1) {
                s += __shfl_xor(s, off); s2 += __shfl_xor(s2, off);
            }
            if (l15 == 0) { redn[row][w][0] = s; redn[row][w][1] = s2; }
        }
    }
    __syncthreads();
    if (t < 16) {
        float s = 0.f, s2 = 0.f;
#pragma unroll
        for (int ww = 0; ww < 16; ++ww) { s += redn[t][ww][0]; s2 += redn[t][ww][1]; }
        float mean = s * (1.f / DIMM);
        float var  = s2 * (1.f / DIMM) - mean * mean;
        stats[t][0] = mean; stats[t][1] = rsqrtf(var + 1e-5f);
    }
    __syncthreads();

    {
        int col = w * 16 + l15;
        float gv = g2[col], bv = b2[col];
#pragma unroll
        for (int r = 0; r < 4; ++r) {
            int row = quad * 4 + r;
            float hv = (x1s[row][col] - stats[row][0]) * stats[row][1] * gv + bv;
            hstage[row][col] = f2bf(hv);
        }
    }
    __syncthreads();

    {
        f32x4 acc[4];
#pragma unroll
        for (int c = 0; c < 4; ++c) acc[c] = (f32x4){0.f, 0.f, 0.f, 0.f};
        const unsigned short* bp = f1T + (size_t)(w * 64 + l15) * 256 + quad * 8;
        bf16x8 bA[4], bB[4];
#pragma unroll
        for (int c = 0; c < 4; ++c) bA[c] = *(const bf16x8*)(bp + (size_t)(c * 16) * 256);
#pragma unroll
        for (int ch = 0; ch < 8; ++ch) {
            bf16x8 a = *(const bf16x8*)&hstage[l15][ch * 32 + quad * 8];
            if (ch + 1 < 8) {
#pragma unroll
                for (int c = 0; c < 4; ++c)
                    bB[c] = *(const bf16x8*)(bp + (size_t)(c * 16) * 256 + (ch + 1) * 32);
            }
#pragma unroll
            for (int c = 0; c < 4; ++c)
                acc[c] = __builtin_amdgcn_mfma_f32_16x16x32_bf16(a, bA[c], acc[c], 0, 0, 0);
#pragma unroll
            for (int c = 0; c < 4; ++c) bA[c] = bB[c];
        }
#pragma unroll
        for (int c = 0; c < 4; ++c) {
            int col = w * 64 + c * 16 + l15;
            float bs = ffn_b1[col];
#pragma unroll
            for (int r = 0; r < 4; ++r) {
                float v = acc[c][r] + bs;
                float x2 = v * v;
                float p = v * fmaf(0.07135481f, x2, 1.5957691f);
                float e = __expf(p);
                float gl = v * (e / (e + 1.f));
                midstage[quad * 4 + r][col] = f2bf(gl);
            }
        }
    }
    __syncthreads();

    {
        int col = w * 16 + l15;
        f32x4 acc = (f32x4){0.f, 0.f, 0.f, 0.f};
        const unsigned short* bp = f2T + (size_t)col * 1024 + quad * 8;
        bf16x8 sb[4];
#pragma unroll
        for (int i = 0; i < 4; ++i) sb[i] = *(const bf16x8*)(bp + i * 32);
#pragma unroll
        for (int ch = 0; ch < 32; ++ch) {
            bf16x8 a = *(const bf16x8*)&midstage[l15][ch * 32 + quad * 8];
            acc = __builtin_amdgcn_mfma_f32_16x16x32_bf16(a, sb[ch & 3], acc, 0, 0, 0);
            if (ch + 4 < 32) sb[ch & 3] = *(const bf16x8*)(bp + (ch + 4) * 32);
        }
        float bs = ffn_b2[col];
#pragma unroll
        for (int r = 0; r < 4; ++r) {
            int row = quad * 4 + r, grow = grow0 + row;
            float mk = (float)get_mask(nmask, fm, grow);
            out[(size_t)grow * DIMM + col] = x1s[row][col] + (acc[r] + bs) * mk;
        }
    }
}

// ---------------- launch ----------------
extern "C" void kernel_launch(void* const* d_in, const int* in_sizes, int n_in,
                              void* d_out, int out_size, void* d_ws, size_t ws_size,
                              hipStream_t stream) {
    const float* x       = (const float*)d_in[0];
    const int*   etypes  = (const int*)d_in[1];
    const void*  nmask   = d_in[2];
    const float* qkv_w   = (const float*)d_in[3];
    const float* qkv_b   = (const float*)d_in[4];
    const float* proj_w  = (const float*)d_in[5];
    const float* proj_b  = (const float*)d_in[6];
    const float* table   = (const float*)d_in[7];
    const float* ln1_g   = (const float*)d_in[8];
    const float* ln1_b   = (const float*)d_in[9];
    const float* ln2_g   = (const float*)d_in[10];
    const float* ln2_b   = (const float*)d_in[11];
    const float* ffn_w1  = (const float*)d_in[12];
    const float* ffn_b1  = (const float*)d_in[13];
    const float* ffn_w2  = (const float*)d_in[14];
    const float* ffn_b2  = (const float*)d_in[15];
    float* out = (float*)d_out;
    float* ws  = (float*)d_ws;

    float* lpart = ws;                               // 131,072 f (512 KB)
    unsigned short* ub = (unsigned short*)(ws + 131072);
    unsigned short* h_ln   = ub;                     // 1,048,576 us
    unsigned short* qkvh   = ub + 1048576;           // 2,097,152
    unsigned short* vT     = ub + 3145728;           // 1,048,576
    unsigned short* OpH    = ub + 4194304;           // 4,194,304 (4 splits)
    unsigned short* qkvT   = ub + 8388608;           // 196,608
    unsigned short* projT  = ub + 8585216;           // 65,536
    unsigned short* f1T    = ub + 8650752;           // 262,144
    unsigned short* f2T    = ub + 8912896;           // 262,144
    unsigned char* emaskP  = (unsigned char*)(ub + 9175040);  // 8,388,608 B

    prep_kernel<<<dim3(2752), dim3(256), 0, stream>>>(
        qkv_w, proj_w, ffn_w1, ffn_w2, qkvT, projT, f1T, f2T,
        x, ln1_g, ln1_b, h_ln, etypes, nmask, emaskP);
    gemm_qkv_mfma<<<dim3(12, 64), dim3(256), 0, stream>>>(h_ln, qkvT, qkv_b, qkvh, vT);
    attn_mfma<<<dim3(HEADS, NB/64, BB*4), dim3(256), 0, stream>>>(
        qkvh, vT, emaskP, table, OpH, lpart);
    megaback<<<dim3(ROWS/16), dim3(1024), 0, stream>>>(
        OpH, lpart, projT, proj_b, x, nmask, ln2_g, ln2_b,
        f1T, ffn_b1, f2T, ffn_b2, out);
}